// Round 2
// baseline (948.000 us; speedup 1.0000x reference)
//
#include <hip/hip_runtime.h>
#include <hip/hip_bf16.h>

// GCN forward, CSR-gather, fused gather+GEMM with PRODUCER/CONSUMER waves.
// 512-thread blocks = 8 waves: 6 producer waves gather a 24-node tile into
// double-buffered LDS; 2 consumer waves GEMM(+relu(+pool)) the previous tile.
// Producers never stop issuing gather loads -> memory pipe stays saturated
// (the plain fused version serialized phases per-wave and dropped to 2.6 TB/s
// vs the 3.86 TB/s standalone-gather plateau). Barrier interval ~28 us, so
// s_barrier overhead is negligible.

#define NN 100000
#define NE 1600000
#define NG 512
#define NBLK ((NN + 1023) / 1024)   // 98 scan blocks
#define T2 24                        // tile nodes for producer/consumer kernels
#define NT ((NN + T2 - 1) / T2)      // 4167 tiles

// ---------------- CSR build (counting sort by dst) ----------------

__global__ void k_zero_int(int* p, int n) {
    int i = blockIdx.x * blockDim.x + threadIdx.x;
    if (i < n) p[i] = 0;
}

__global__ void k_hist(const int* __restrict__ dst, int* cnt, int e) {
    int i = blockIdx.x * blockDim.x + threadIdx.x;
    if (i < e) atomicAdd(&cnt[dst[i]], 1);
}

// fused: dinv[i] = rsqrt(cnt[i]+1)  and  gmax zero-init (NG*256 = 131072)
__global__ void k_prep(const int* __restrict__ cnt, float* __restrict__ dinv,
                       float* __restrict__ gmax) {
    int i = blockIdx.x * blockDim.x + threadIdx.x;
    if (i < NN) dinv[i] = rsqrtf((float)cnt[i] + 1.0f);
    if (i < NG * 256) gmax[i] = 0.0f;
}

__global__ __launch_bounds__(256) void k_bsum(const int* __restrict__ cnt, int* __restrict__ bsum) {
    __shared__ int s[256];
    int b = blockIdx.x, t = threadIdx.x;
    int base = b * 1024 + t * 4;
    int v = 0;
#pragma unroll
    for (int j = 0; j < 4; j++) { int i = base + j; if (i < NN) v += cnt[i]; }
    s[t] = v; __syncthreads();
    for (int off = 128; off > 0; off >>= 1) {
        if (t < off) s[t] += s[t + off];
        __syncthreads();
    }
    if (t == 0) bsum[b] = s[0];
}

__global__ __launch_bounds__(128) void k_scan_bsum(int* bsum, int* row_ptr) {
    __shared__ int s[128];
    int t = threadIdx.x;
    int v = (t < NBLK) ? bsum[t] : 0;
    s[t] = v; __syncthreads();
    for (int off = 1; off < 128; off <<= 1) {
        int u = (t >= off) ? s[t - off] : 0;
        __syncthreads();
        s[t] += u;
        __syncthreads();
    }
    if (t < NBLK) bsum[t] = s[t] - v;
    if (t == 0) row_ptr[NN] = NE;
}

__global__ __launch_bounds__(256) void k_scan_blocks(const int* __restrict__ cnt,
    const int* __restrict__ bsum, int* __restrict__ row_ptr, int* __restrict__ cursor) {
    __shared__ int s[256];
    int b = blockIdx.x, t = threadIdx.x;
    int base = b * 1024 + t * 4;
    int v[4]; int sum = 0;
#pragma unroll
    for (int j = 0; j < 4; j++) { int i = base + j; v[j] = (i < NN) ? cnt[i] : 0; sum += v[j]; }
    s[t] = sum; __syncthreads();
    for (int off = 1; off < 256; off <<= 1) {
        int u = (t >= off) ? s[t - off] : 0;
        __syncthreads();
        s[t] += u;
        __syncthreads();
    }
    int excl = s[t] - sum + bsum[b];
#pragma unroll
    for (int j = 0; j < 4; j++) {
        int i = base + j;
        if (i < NN) { row_ptr[i] = excl; cursor[i] = excl; excl += v[j]; }
    }
}

// counting-sort fill: one packed 8B store per edge: es[pos] = {src, w}
__global__ void k_fillslots(const int* __restrict__ src, const int* __restrict__ dst,
    const float* __restrict__ dinv, int* cursor, int2* __restrict__ es, int e) {
    int i = blockIdx.x * blockDim.x + threadIdx.x;
    if (i >= e) return;
    int s = src[i], d = dst[i];
    int pos = atomicAdd(&cursor[d], 1);
    es[pos] = make_int2(s, __float_as_int(dinv[s] * dinv[d]));
}

// ---------------- fused1 (producer/consumer): gather78 + gemm1 ----------------
// 8 waves: wv 0..5 gather 4 nodes each (lanes 0..38, float2) into As[buf];
// wv 6..7 GEMM 12 nodes each from As[buf^1]: lane covers 2 of 128 out-feats,
// A wave-uniform LDS broadcast, W1 rows coalesced from L1/L2. relu -> h1.
__global__ __launch_bounds__(512) void k_fused1_pc(const float* __restrict__ x,
    const int* __restrict__ rp, const int2* __restrict__ es,
    const float* __restrict__ dinv, const float* __restrict__ W,
    const float* __restrict__ bias, float* __restrict__ out) {
    __shared__ float As[2][T2][80];   // 15.4 KB
    int tid = threadIdx.x;
    int wv = tid >> 6, l = tid & 63;
    int t = blockIdx.x;
    const int G = gridDim.x;
    int tprev = -1;
    int pbuf = 0;

    while (t < NT || tprev >= 0) {
        if (wv < 6) {
            if (t < NT && l < 39) {
#pragma unroll 1
                for (int i = 0; i < 4; i++) {
                    int li = wv * 4 + i;
                    int n = t * T2 + li;
                    if (n < NN) {
                        float di = dinv[n], sw = di * di;
                        float2 a = ((const float2*)(x + (size_t)n * 78))[l];
                        a.x *= sw; a.y *= sw;
                        int e = rp[n], e1 = rp[n + 1];
                        int nf = (e1 - e) >> 3;
                        if (nf > 0) {
                            int2 cur[8];
#pragma unroll
                            for (int j = 0; j < 8; j++) cur[j] = es[e + j];
                            for (int b = 1; ; b++) {
                                float2 v[8];
#pragma unroll
                                for (int j = 0; j < 8; j++)
                                    v[j] = ((const float2*)(x + (size_t)cur[j].x * 78))[l];
                                e += 8;
                                bool more = (b < nf);
                                int2 nxt[8];
                                if (more) {
#pragma unroll
                                    for (int j = 0; j < 8; j++) nxt[j] = es[e + j];
                                }
#pragma unroll
                                for (int j = 0; j < 8; j++) {
                                    float w = __int_as_float(cur[j].y);
                                    a.x += v[j].x * w; a.y += v[j].y * w;
                                }
                                if (!more) break;
#pragma unroll
                                for (int j = 0; j < 8; j++) cur[j] = nxt[j];
                            }
                        }
                        for (; e < e1; e++) {
                            int2 p = es[e];
                            float w = __int_as_float(p.y);
                            float2 v = ((const float2*)(x + (size_t)p.x * 78))[l];
                            a.x += v.x * w; a.y += v.y * w;
                        }
                        *(float2*)&As[pbuf][li][2 * l] = a;
                    }
                }
            }
        } else if (tprev >= 0) {
            int cw = wv - 6;            // 0 or 1
            int rb = pbuf ^ 1;
            int base = cw * 12;
            int f0 = l * 2;
            float2 acc[12];
#pragma unroll
            for (int i = 0; i < 12; i++) acc[i] = make_float2(0.f, 0.f);

            for (int k = 0; k < 76; k += 4) {
                float2 w0 = *(const float2*)&W[(k + 0) * 128 + f0];
                float2 w1 = *(const float2*)&W[(k + 1) * 128 + f0];
                float2 w2 = *(const float2*)&W[(k + 2) * 128 + f0];
                float2 w3 = *(const float2*)&W[(k + 3) * 128 + f0];
#pragma unroll
                for (int i = 0; i < 12; i++) {
                    float4 a = *(const float4*)&As[rb][base + i][k];
                    acc[i].x += a.x * w0.x + a.y * w1.x + a.z * w2.x + a.w * w3.x;
                    acc[i].y += a.x * w0.y + a.y * w1.y + a.z * w2.y + a.w * w3.y;
                }
            }
            {   // rows 76,77
                float2 w0 = *(const float2*)&W[76 * 128 + f0];
                float2 w1 = *(const float2*)&W[77 * 128 + f0];
#pragma unroll
                for (int i = 0; i < 12; i++) {
                    float2 a = *(const float2*)&As[rb][base + i][76];
                    acc[i].x += a.x * w0.x + a.y * w1.x;
                    acc[i].y += a.x * w0.y + a.y * w1.y;
                }
            }
            float2 bv = *(const float2*)&bias[f0];
#pragma unroll
            for (int i = 0; i < 12; i++) {
                int n = tprev * T2 + base + i;
                if (n < NN) {
                    float2 o;
                    o.x = fmaxf(acc[i].x + bv.x, 0.f);
                    o.y = fmaxf(acc[i].y + bv.y, 0.f);
                    *(float2*)&out[(size_t)n * 128 + f0] = o;
                }
            }
        }
        __syncthreads();
        tprev = (t < NT) ? t : -1;
        t += G;
        pbuf ^= 1;
    }
}

// ---------------- fused2 (producer/consumer): gather128 + gemm2 + pool ----------------
// Same skeleton; producers use all 64 lanes (float2 x 64 = 128 feats);
// consumers: lane covers 4 of 256 out-feats; pool via flush-on-change
// segment-max (batch sorted) with atomicMax.
__global__ __launch_bounds__(512) void k_fused2_pc(const float* __restrict__ h,
    const int* __restrict__ rp, const int2* __restrict__ es,
    const float* __restrict__ dinv, const float* __restrict__ W,
    const float* __restrict__ bias, const int* __restrict__ batch,
    unsigned* __restrict__ gmax) {
    __shared__ float As[2][T2][128];  // 24 KB
    int tid = threadIdx.x;
    int wv = tid >> 6, l = tid & 63;
    int t = blockIdx.x;
    const int G = gridDim.x;
    int tprev = -1;
    int pbuf = 0;

    while (t < NT || tprev >= 0) {
        if (wv < 6) {
            if (t < NT) {
#pragma unroll 1
                for (int i = 0; i < 4; i++) {
                    int li = wv * 4 + i;
                    int n = t * T2 + li;
                    if (n < NN) {
                        float di = dinv[n], sw = di * di;
                        float2 a = ((const float2*)(h + (size_t)n * 128))[l];
                        a.x *= sw; a.y *= sw;
                        int e = rp[n], e1 = rp[n + 1];
                        int nf = (e1 - e) >> 3;
                        if (nf > 0) {
                            int2 cur[8];
#pragma unroll
                            for (int j = 0; j < 8; j++) cur[j] = es[e + j];
                            for (int b = 1; ; b++) {
                                float2 v[8];
#pragma unroll
                                for (int j = 0; j < 8; j++)
                                    v[j] = ((const float2*)(h + (size_t)cur[j].x * 128))[l];
                                e += 8;
                                bool more = (b < nf);
                                int2 nxt[8];
                                if (more) {
#pragma unroll
                                    for (int j = 0; j < 8; j++) nxt[j] = es[e + j];
                                }
#pragma unroll
                                for (int j = 0; j < 8; j++) {
                                    float w = __int_as_float(cur[j].y);
                                    a.x += v[j].x * w; a.y += v[j].y * w;
                                }
                                if (!more) break;
#pragma unroll
                                for (int j = 0; j < 8; j++) cur[j] = nxt[j];
                            }
                        }
                        for (; e < e1; e++) {
                            int2 p = es[e];
                            float w = __int_as_float(p.y);
                            float2 v = ((const float2*)(h + (size_t)p.x * 128))[l];
                            a.x += v.x * w; a.y += v.y * w;
                        }
                        *(float2*)&As[pbuf][li][2 * l] = a;
                    }
                }
            }
        } else if (tprev >= 0) {
            int cw = wv - 6;            // 0 or 1
            int rb = pbuf ^ 1;
            int base = cw * 12;
            int f0 = l * 4;
            float4 acc[12];
#pragma unroll
            for (int i = 0; i < 12; i++) acc[i] = make_float4(0.f, 0.f, 0.f, 0.f);

            for (int k = 0; k < 128; k += 4) {
                float4 w0 = *(const float4*)&W[(size_t)(k + 0) * 256 + f0];
                float4 w1 = *(const float4*)&W[(size_t)(k + 1) * 256 + f0];
                float4 w2 = *(const float4*)&W[(size_t)(k + 2) * 256 + f0];
                float4 w3 = *(const float4*)&W[(size_t)(k + 3) * 256 + f0];
#pragma unroll
                for (int i = 0; i < 12; i++) {
                    float4 a = *(const float4*)&As[rb][base + i][k];
                    acc[i].x += a.x * w0.x + a.y * w1.x + a.z * w2.x + a.w * w3.x;
                    acc[i].y += a.x * w0.y + a.y * w1.y + a.z * w2.y + a.w * w3.y;
                    acc[i].z += a.x * w0.z + a.y * w1.z + a.z * w2.z + a.w * w3.z;
                    acc[i].w += a.x * w0.w + a.y * w1.w + a.z * w2.w + a.w * w3.w;
                }
            }

            float4 bv = *(const float4*)&bias[f0];
            int curg = -1;
            float4 m = make_float4(0.f, 0.f, 0.f, 0.f);
#pragma unroll
            for (int i = 0; i < 12; i++) {
                int n = tprev * T2 + base + i;
                if (n < NN) {
                    int g = batch[n];
                    float4 v;
                    v.x = fmaxf(acc[i].x + bv.x, 0.f); v.y = fmaxf(acc[i].y + bv.y, 0.f);
                    v.z = fmaxf(acc[i].z + bv.z, 0.f); v.w = fmaxf(acc[i].w + bv.w, 0.f);
                    if (g != curg) {
                        if (curg >= 0) {
                            unsigned* gp = &gmax[(size_t)curg * 256 + f0];
                            atomicMax(&gp[0], __float_as_uint(m.x));
                            atomicMax(&gp[1], __float_as_uint(m.y));
                            atomicMax(&gp[2], __float_as_uint(m.z));
                            atomicMax(&gp[3], __float_as_uint(m.w));
                        }
                        curg = g; m = v;
                    } else {
                        m.x = fmaxf(m.x, v.x); m.y = fmaxf(m.y, v.y);
                        m.z = fmaxf(m.z, v.z); m.w = fmaxf(m.w, v.w);
                    }
                }
            }
            if (curg >= 0) {
                unsigned* gp = &gmax[(size_t)curg * 256 + f0];
                atomicMax(&gp[0], __float_as_uint(m.x));
                atomicMax(&gp[1], __float_as_uint(m.y));
                atomicMax(&gp[2], __float_as_uint(m.z));
                atomicMax(&gp[3], __float_as_uint(m.w));
            }
        }
        __syncthreads();
        tprev = (t < NT) ? t : -1;
        t += G;
        pbuf ^= 1;
    }
}

// ---------------- MLP head ----------------

__global__ __launch_bounds__(256) void k_gemm3(const float* __restrict__ A,
    const float* __restrict__ W, const float* __restrict__ bias,
    float* __restrict__ out) {
    __shared__ float rs[256];
    int g = blockIdx.x, tid = threadIdx.x;
    rs[tid] = A[g * 256 + tid];
    __syncthreads();
    float acc[4] = {0.f, 0.f, 0.f, 0.f};
    for (int k = 0; k < 256; k++) {
        float a = rs[k];
#pragma unroll
        for (int j = 0; j < 4; j++) acc[j] += a * W[k * 1024 + tid + j * 256];
    }
#pragma unroll
    for (int j = 0; j < 4; j++) {
        int f = tid + j * 256;
        out[g * 1024 + f] = fmaxf(acc[j] + bias[f], 0.0f);
    }
}

__global__ __launch_bounds__(128) void k_gemm4(const float* __restrict__ A,
    const float* __restrict__ W, const float* __restrict__ bias,
    float* __restrict__ out) {
    __shared__ float rs[1024];
    int g = blockIdx.x, tid = threadIdx.x;
    for (int i = tid; i < 1024; i += 128) rs[i] = A[g * 1024 + i];
    __syncthreads();
    float acc = 0.0f;
    for (int k = 0; k < 1024; k++) acc += rs[k] * W[k * 128 + tid];
    out[g * 128 + tid] = acc + bias[tid];
}

extern "C" void kernel_launch(void* const* d_in, const int* in_sizes, int n_in,
                              void* d_out, int out_size, void* d_ws, size_t ws_size,
                              hipStream_t stream) {
    const float* x    = (const float*)d_in[0];
    const int*   ei   = (const int*)d_in[1];
    const int*   batch= (const int*)d_in[2];
    const float* W1   = (const float*)d_in[3];
    const float* b1   = (const float*)d_in[4];
    const float* W2   = (const float*)d_in[5];
    const float* b2   = (const float*)d_in[6];
    const float* Wg1  = (const float*)d_in[7];
    const float* bg1  = (const float*)d_in[8];
    const float* Wg2  = (const float*)d_in[9];
    const float* bg2  = (const float*)d_in[10];
    const int* src = ei;
    const int* dst = ei + NE;

    char* w8 = (char*)d_ws;
    int*   cnt     = (int*)w8;                 w8 += (size_t)NN * 4;
    int*   row_ptr = (int*)w8;                 w8 += (size_t)(NN + 4) * 4;
    int*   cursor  = (int*)w8;                 w8 += (size_t)NN * 4;
    int*   bsum    = (int*)w8;                 w8 += 128 * 4;
    int2*  es      = (int2*)w8;                w8 += (size_t)NE * 8;
    float* dinv    = (float*)w8;               w8 += (size_t)NN * 4;
    float* h1      = (float*)w8;               w8 += (size_t)NN * 128 * 4;
    unsigned* gmax = (unsigned*)w8;            w8 += (size_t)NG * 256 * 4;
    float* g1      = (float*)w8;               w8 += (size_t)NG * 1024 * 4;

    // CSR build
    k_zero_int<<<(NN + 255) / 256, 256, 0, stream>>>(cnt, NN);
    k_hist<<<(NE + 255) / 256, 256, 0, stream>>>(dst, cnt, NE);
    k_prep<<<(NG * 256 + 255) / 256, 256, 0, stream>>>(cnt, dinv, (float*)gmax);
    k_bsum<<<NBLK, 256, 0, stream>>>(cnt, bsum);
    k_scan_bsum<<<1, 128, 0, stream>>>(bsum, row_ptr);
    k_scan_blocks<<<NBLK, 256, 0, stream>>>(cnt, bsum, row_ptr, cursor);
    k_fillslots<<<(NE + 255) / 256, 256, 0, stream>>>(src, dst, dinv, cursor, es, NE);

    // layer 1 (producer/consumer fused gather + gemm + relu)
    k_fused1_pc<<<1024, 512, 0, stream>>>(x, row_ptr, es, dinv, W1, b1, h1);

    // layer 2 (producer/consumer fused gather + gemm + relu + pool)
    k_fused2_pc<<<1024, 512, 0, stream>>>(h1, row_ptr, es, dinv, W2, b2, batch, gmax);

    // MLP head
    k_gemm3<<<NG, 256, 0, stream>>>((const float*)gmax, Wg1, bg1, g1);
    k_gemm4<<<NG, 128, 0, stream>>>(g1, Wg2, bg2, (float*)d_out);
}

// Round 4
// 587.486 us; speedup vs baseline: 1.6137x; 1.6137x over previous
//
#include <hip/hip_runtime.h>
#include <hip/hip_bf16.h>

// GCN forward, CSR-gather, fused gather+GEMM (barrier-free, per-wave phases).
// vs prev best (626us): gather is PAIR-ZIPPED (2 nodes x 8-deep chunk pipeline
// per wave -> ~16 random rows in flight instead of 8). Rationale: measured BW
// tracks (waves actively gathering) -> the random-row stream is concurrency-
// limited, so more outstanding rows per wave = more bandwidth. Node index is
// wave-uniform so all zip branches are uniform (no divergence).
// R3 crash was a grid off-by-one in fused1 (3126 blocks -> task 12500+ ->
// rp OOB -> es[garbage]); fixed: grid = NN/32 = 3125 exactly + guard.

#define NN 100000
#define NE 1600000
#define NG 512
#define NBLK ((NN + 1023) / 1024)   // 98 scan blocks

typedef float v2f __attribute__((ext_vector_type(2)));

// ---------------- CSR build (counting sort by dst) ----------------

__global__ void k_zero_int(int* p, int n) {
    int i = blockIdx.x * blockDim.x + threadIdx.x;
    if (i < n) p[i] = 0;
}

__global__ void k_hist(const int* __restrict__ dst, int* cnt, int e) {
    int i = blockIdx.x * blockDim.x + threadIdx.x;
    if (i < e) atomicAdd(&cnt[dst[i]], 1);
}

// fused: dinv[i] = rsqrt(cnt[i]+1)  and  gmax zero-init (NG*256 = 131072)
__global__ void k_prep(const int* __restrict__ cnt, float* __restrict__ dinv,
                       float* __restrict__ gmax) {
    int i = blockIdx.x * blockDim.x + threadIdx.x;
    if (i < NN) dinv[i] = rsqrtf((float)cnt[i] + 1.0f);
    if (i < NG * 256) gmax[i] = 0.0f;
}

__global__ __launch_bounds__(256) void k_bsum(const int* __restrict__ cnt, int* __restrict__ bsum) {
    __shared__ int s[256];
    int b = blockIdx.x, t = threadIdx.x;
    int base = b * 1024 + t * 4;
    int v = 0;
#pragma unroll
    for (int j = 0; j < 4; j++) { int i = base + j; if (i < NN) v += cnt[i]; }
    s[t] = v; __syncthreads();
    for (int off = 128; off > 0; off >>= 1) {
        if (t < off) s[t] += s[t + off];
        __syncthreads();
    }
    if (t == 0) bsum[b] = s[0];
}

__global__ __launch_bounds__(128) void k_scan_bsum(int* bsum, int* row_ptr) {
    __shared__ int s[128];
    int t = threadIdx.x;
    int v = (t < NBLK) ? bsum[t] : 0;
    s[t] = v; __syncthreads();
    for (int off = 1; off < 128; off <<= 1) {
        int u = (t >= off) ? s[t - off] : 0;
        __syncthreads();
        s[t] += u;
        __syncthreads();
    }
    if (t < NBLK) bsum[t] = s[t] - v;
    if (t == 0) row_ptr[NN] = NE;
}

__global__ __launch_bounds__(256) void k_scan_blocks(const int* __restrict__ cnt,
    const int* __restrict__ bsum, int* __restrict__ row_ptr, int* __restrict__ cursor) {
    __shared__ int s[256];
    int b = blockIdx.x, t = threadIdx.x;
    int base = b * 1024 + t * 4;
    int v[4]; int sum = 0;
#pragma unroll
    for (int j = 0; j < 4; j++) { int i = base + j; v[j] = (i < NN) ? cnt[i] : 0; sum += v[j]; }
    s[t] = sum; __syncthreads();
    for (int off = 1; off < 256; off <<= 1) {
        int u = (t >= off) ? s[t - off] : 0;
        __syncthreads();
        s[t] += u;
        __syncthreads();
    }
    int excl = s[t] - sum + bsum[b];
#pragma unroll
    for (int j = 0; j < 4; j++) {
        int i = base + j;
        if (i < NN) { row_ptr[i] = excl; cursor[i] = excl; excl += v[j]; }
    }
}

// counting-sort fill: one packed 8B store per edge: es[pos] = {src, w}
__global__ void k_fillslots(const int* __restrict__ src, const int* __restrict__ dst,
    const float* __restrict__ dinv, int* cursor, int2* __restrict__ es, int e) {
    int i = blockIdx.x * blockDim.x + threadIdx.x;
    if (i >= e) return;
    int s = src[i], d = dst[i];
    int pos = atomicAdd(&cursor[d], 1);
    es[pos] = make_int2(s, __float_as_int(dinv[s] * dinv[d]));
}

// ---------------- fused1: pair-zip gather78 + gemm1 ----------------
// 4 waves/block, wave owns 8 nodes (4 pairs). Gather lanes 0..38 (float2).
// GEMM: lane covers 2 of 128 out-feats; A wave-uniform LDS broadcast; W1 rows
// coalesced from L1/L2. relu -> h1.
__global__ __launch_bounds__(256) void k_fused1(const float* __restrict__ x,
    const int* __restrict__ rp, const int2* __restrict__ es,
    const float* __restrict__ dinv, const float* __restrict__ W,
    const float* __restrict__ bias, float* __restrict__ out) {
    __shared__ float As[4][8][80];   // 10 KB
    int tid = threadIdx.x;
    int wv = tid >> 6, l = tid & 63;
    int task = __builtin_amdgcn_readfirstlane(blockIdx.x * 4 + wv);  // 12500 tasks
    int n0 = task * 8;
    if (n0 >= NN) return;

    if (l < 39) {
        for (int pi = 0; pi < 4; pi++) {
            int nA = n0 + 2 * pi, nB = nA + 1;
            float diA = dinv[nA], swA = diA * diA;
            float diB = dinv[nB], swB = diB * diB;
            float2 aA = ((const float2*)(x + (size_t)nA * 78))[l];
            float2 aB = ((const float2*)(x + (size_t)nB * 78))[l];
            aA.x *= swA; aA.y *= swA;
            aB.x *= swB; aB.y *= swB;
            int eA = rp[nA], eA1 = rp[nA + 1];
            int eB = rp[nB], eB1 = rp[nB + 1];
            int cA = (eA1 - eA) >> 3, cB = (eB1 - eB) >> 3;
            while (cA > 0 || cB > 0) {
                bool dA = (cA > 0), dB = (cB > 0);
                int2 esA[8], esB[8];
                float2 vA[8], vB[8];
                if (dA) {
#pragma unroll
                    for (int j = 0; j < 8; j++) esA[j] = es[eA + j];
                }
                if (dB) {
#pragma unroll
                    for (int j = 0; j < 8; j++) esB[j] = es[eB + j];
                }
                if (dA) {
#pragma unroll
                    for (int j = 0; j < 8; j++)
                        vA[j] = ((const float2*)(x + (size_t)esA[j].x * 78))[l];
                }
                if (dB) {
#pragma unroll
                    for (int j = 0; j < 8; j++)
                        vB[j] = ((const float2*)(x + (size_t)esB[j].x * 78))[l];
                }
                if (dA) {
#pragma unroll
                    for (int j = 0; j < 8; j++) {
                        float w = __int_as_float(esA[j].y);
                        aA.x += vA[j].x * w; aA.y += vA[j].y * w;
                    }
                    eA += 8; cA--;
                }
                if (dB) {
#pragma unroll
                    for (int j = 0; j < 8; j++) {
                        float w = __int_as_float(esB[j].y);
                        aB.x += vB[j].x * w; aB.y += vB[j].y * w;
                    }
                    eB += 8; cB--;
                }
            }
            // zipped tails (<8 each)
            while (eA < eA1 && eB < eB1) {
                int2 pA = es[eA], pB = es[eB];
                float2 vA2 = ((const float2*)(x + (size_t)pA.x * 78))[l];
                float2 vB2 = ((const float2*)(x + (size_t)pB.x * 78))[l];
                float wA = __int_as_float(pA.y), wB = __int_as_float(pB.y);
                aA.x += vA2.x * wA; aA.y += vA2.y * wA;
                aB.x += vB2.x * wB; aB.y += vB2.y * wB;
                eA++; eB++;
            }
            for (; eA < eA1; eA++) {
                int2 p = es[eA];
                float w = __int_as_float(p.y);
                float2 v = ((const float2*)(x + (size_t)p.x * 78))[l];
                aA.x += v.x * w; aA.y += v.y * w;
            }
            for (; eB < eB1; eB++) {
                int2 p = es[eB];
                float w = __int_as_float(p.y);
                float2 v = ((const float2*)(x + (size_t)p.x * 78))[l];
                aB.x += v.x * w; aB.y += v.y * w;
            }
            *(float2*)&As[wv][2 * pi][2 * l] = aA;
            *(float2*)&As[wv][2 * pi + 1][2 * l] = aB;
        }
    }
    // same-wave producer/consumer: compiler inserts lgkmcnt waits; no barrier.

    int f0 = l * 2;
    float2 acc[8];
#pragma unroll
    for (int i = 0; i < 8; i++) acc[i] = make_float2(0.f, 0.f);

    for (int k = 0; k < 76; k += 4) {
        float2 w0 = *(const float2*)&W[(k + 0) * 128 + f0];
        float2 w1 = *(const float2*)&W[(k + 1) * 128 + f0];
        float2 w2 = *(const float2*)&W[(k + 2) * 128 + f0];
        float2 w3 = *(const float2*)&W[(k + 3) * 128 + f0];
#pragma unroll
        for (int i = 0; i < 8; i++) {
            float4 a = *(const float4*)&As[wv][i][k];
            acc[i].x += a.x * w0.x + a.y * w1.x + a.z * w2.x + a.w * w3.x;
            acc[i].y += a.x * w0.y + a.y * w1.y + a.z * w2.y + a.w * w3.y;
        }
    }
    {   // rows 76,77
        float2 w0 = *(const float2*)&W[76 * 128 + f0];
        float2 w1 = *(const float2*)&W[77 * 128 + f0];
#pragma unroll
        for (int i = 0; i < 8; i++) {
            float2 a = *(const float2*)&As[wv][i][76];
            acc[i].x += a.x * w0.x + a.y * w1.x;
            acc[i].y += a.x * w0.y + a.y * w1.y;
        }
    }
    float2 bv = *(const float2*)&bias[f0];
#pragma unroll
    for (int i = 0; i < 8; i++) {
        float2 o;
        o.x = fmaxf(acc[i].x + bv.x, 0.f);
        o.y = fmaxf(acc[i].y + bv.y, 0.f);
        *(float2*)&out[(size_t)(n0 + i) * 128 + f0] = o;
    }
}

// ---------------- fused2: pair-zip gather128 + gemm2(pk_fma) + pool ----------------
// 4 waves/block, wave owns 8 nodes (4 pairs); all 64 lanes gather (float2).
// GEMM: lane covers 4 of 256 out-feats, packed-f32 fma; pool: flush-on-change
// segment-max (batch sorted) with atomicMax.
__global__ __launch_bounds__(256) void k_fused2(const float* __restrict__ h,
    const int* __restrict__ rp, const int2* __restrict__ es,
    const float* __restrict__ dinv, const float* __restrict__ W,
    const float* __restrict__ bias, const int* __restrict__ batch,
    unsigned* __restrict__ gmax) {
    __shared__ float As[4][8][128];  // 16 KB
    int tid = threadIdx.x;
    int wv = tid >> 6, l = tid & 63;
    int task = __builtin_amdgcn_readfirstlane(blockIdx.x * 4 + wv);  // 12500 tasks
    int n0 = task * 8;
    if (n0 >= NN) return;

    for (int pi = 0; pi < 4; pi++) {
        int nA = n0 + 2 * pi, nB = nA + 1;
        float diA = dinv[nA], swA = diA * diA;
        float diB = dinv[nB], swB = diB * diB;
        float2 aA = ((const float2*)(h + (size_t)nA * 128))[l];
        float2 aB = ((const float2*)(h + (size_t)nB * 128))[l];
        aA.x *= swA; aA.y *= swA;
        aB.x *= swB; aB.y *= swB;
        int eA = rp[nA], eA1 = rp[nA + 1];
        int eB = rp[nB], eB1 = rp[nB + 1];
        int cA = (eA1 - eA) >> 3, cB = (eB1 - eB) >> 3;
        while (cA > 0 || cB > 0) {
            bool dA = (cA > 0), dB = (cB > 0);
            int2 esA[8], esB[8];
            float2 vA[8], vB[8];
            if (dA) {
#pragma unroll
                for (int j = 0; j < 8; j++) esA[j] = es[eA + j];
            }
            if (dB) {
#pragma unroll
                for (int j = 0; j < 8; j++) esB[j] = es[eB + j];
            }
            if (dA) {
#pragma unroll
                for (int j = 0; j < 8; j++)
                    vA[j] = ((const float2*)(h + (size_t)esA[j].x * 128))[l];
            }
            if (dB) {
#pragma unroll
                for (int j = 0; j < 8; j++)
                    vB[j] = ((const float2*)(h + (size_t)esB[j].x * 128))[l];
            }
            if (dA) {
#pragma unroll
                for (int j = 0; j < 8; j++) {
                    float w = __int_as_float(esA[j].y);
                    aA.x += vA[j].x * w; aA.y += vA[j].y * w;
                }
                eA += 8; cA--;
            }
            if (dB) {
#pragma unroll
                for (int j = 0; j < 8; j++) {
                    float w = __int_as_float(esB[j].y);
                    aB.x += vB[j].x * w; aB.y += vB[j].y * w;
                }
                eB += 8; cB--;
            }
        }
        // zipped tails (<8 each)
        while (eA < eA1 && eB < eB1) {
            int2 pA = es[eA], pB = es[eB];
            float2 vA2 = ((const float2*)(h + (size_t)pA.x * 128))[l];
            float2 vB2 = ((const float2*)(h + (size_t)pB.x * 128))[l];
            float wA = __int_as_float(pA.y), wB = __int_as_float(pB.y);
            aA.x += vA2.x * wA; aA.y += vA2.y * wA;
            aB.x += vB2.x * wB; aB.y += vB2.y * wB;
            eA++; eB++;
        }
        for (; eA < eA1; eA++) {
            int2 p = es[eA];
            float w = __int_as_float(p.y);
            float2 v = ((const float2*)(h + (size_t)p.x * 128))[l];
            aA.x += v.x * w; aA.y += v.y * w;
        }
        for (; eB < eB1; eB++) {
            int2 p = es[eB];
            float w = __int_as_float(p.y);
            float2 v = ((const float2*)(h + (size_t)p.x * 128))[l];
            aB.x += v.x * w; aB.y += v.y * w;
        }
        *(float2*)&As[wv][2 * pi][2 * l] = aA;
        *(float2*)&As[wv][2 * pi + 1][2 * l] = aB;
    }
    // same-wave producer/consumer: no barrier needed.

    int f0 = l * 4;
    v2f acc[8][2];
#pragma unroll
    for (int i = 0; i < 8; i++) { acc[i][0] = (v2f)(0.f); acc[i][1] = (v2f)(0.f); }

    for (int k = 0; k < 128; k += 4) {
        float4 w0 = *(const float4*)&W[(size_t)(k + 0) * 256 + f0];
        float4 w1 = *(const float4*)&W[(size_t)(k + 1) * 256 + f0];
        float4 w2 = *(const float4*)&W[(size_t)(k + 2) * 256 + f0];
        float4 w3 = *(const float4*)&W[(size_t)(k + 3) * 256 + f0];
        v2f w0a = {w0.x, w0.y}, w0b = {w0.z, w0.w};
        v2f w1a = {w1.x, w1.y}, w1b = {w1.z, w1.w};
        v2f w2a = {w2.x, w2.y}, w2b = {w2.z, w2.w};
        v2f w3a = {w3.x, w3.y}, w3b = {w3.z, w3.w};
#pragma unroll
        for (int i = 0; i < 8; i++) {
            float4 a = *(const float4*)&As[wv][i][k];
            v2f sx = {a.x, a.x}, sy = {a.y, a.y}, sz = {a.z, a.z}, sw = {a.w, a.w};
            acc[i][0] = __builtin_elementwise_fma(sx, w0a, acc[i][0]);
            acc[i][1] = __builtin_elementwise_fma(sx, w0b, acc[i][1]);
            acc[i][0] = __builtin_elementwise_fma(sy, w1a, acc[i][0]);
            acc[i][1] = __builtin_elementwise_fma(sy, w1b, acc[i][1]);
            acc[i][0] = __builtin_elementwise_fma(sz, w2a, acc[i][0]);
            acc[i][1] = __builtin_elementwise_fma(sz, w2b, acc[i][1]);
            acc[i][0] = __builtin_elementwise_fma(sw, w3a, acc[i][0]);
            acc[i][1] = __builtin_elementwise_fma(sw, w3b, acc[i][1]);
        }
    }

    float4 bv = *(const float4*)&bias[f0];
    int curg = -1;
    float4 m = make_float4(0.f, 0.f, 0.f, 0.f);
#pragma unroll
    for (int i = 0; i < 8; i++) {
        int g = batch[n0 + i];
        float4 v;
        v.x = fmaxf(acc[i][0].x + bv.x, 0.f); v.y = fmaxf(acc[i][0].y + bv.y, 0.f);
        v.z = fmaxf(acc[i][1].x + bv.z, 0.f); v.w = fmaxf(acc[i][1].y + bv.w, 0.f);
        if (g != curg) {
            if (curg >= 0) {
                unsigned* gp = &gmax[(size_t)curg * 256 + f0];
                atomicMax(&gp[0], __float_as_uint(m.x));
                atomicMax(&gp[1], __float_as_uint(m.y));
                atomicMax(&gp[2], __float_as_uint(m.z));
                atomicMax(&gp[3], __float_as_uint(m.w));
            }
            curg = g; m = v;
        } else {
            m.x = fmaxf(m.x, v.x); m.y = fmaxf(m.y, v.y);
            m.z = fmaxf(m.z, v.z); m.w = fmaxf(m.w, v.w);
        }
    }
    if (curg >= 0) {
        unsigned* gp = &gmax[(size_t)curg * 256 + f0];
        atomicMax(&gp[0], __float_as_uint(m.x));
        atomicMax(&gp[1], __float_as_uint(m.y));
        atomicMax(&gp[2], __float_as_uint(m.z));
        atomicMax(&gp[3], __float_as_uint(m.w));
    }
}

// ---------------- MLP head ----------------

__global__ __launch_bounds__(256) void k_gemm3(const float* __restrict__ A,
    const float* __restrict__ W, const float* __restrict__ bias,
    float* __restrict__ out) {
    __shared__ float rs[256];
    int g = blockIdx.x, tid = threadIdx.x;
    rs[tid] = A[g * 256 + tid];
    __syncthreads();
    float acc[4] = {0.f, 0.f, 0.f, 0.f};
    for (int k = 0; k < 256; k++) {
        float a = rs[k];
#pragma unroll
        for (int j = 0; j < 4; j++) acc[j] += a * W[k * 1024 + tid + j * 256];
    }
#pragma unroll
    for (int j = 0; j < 4; j++) {
        int f = tid + j * 256;
        out[g * 1024 + f] = fmaxf(acc[j] + bias[f], 0.0f);
    }
}

__global__ __launch_bounds__(128) void k_gemm4(const float* __restrict__ A,
    const float* __restrict__ W, const float* __restrict__ bias,
    float* __restrict__ out) {
    __shared__ float rs[1024];
    int g = blockIdx.x, tid = threadIdx.x;
    for (int i = tid; i < 1024; i += 128) rs[i] = A[g * 1024 + i];
    __syncthreads();
    float acc = 0.0f;
    for (int k = 0; k < 1024; k++) acc += rs[k] * W[k * 128 + tid];
    out[g * 128 + tid] = acc + bias[tid];
}

extern "C" void kernel_launch(void* const* d_in, const int* in_sizes, int n_in,
                              void* d_out, int out_size, void* d_ws, size_t ws_size,
                              hipStream_t stream) {
    const float* x    = (const float*)d_in[0];
    const int*   ei   = (const int*)d_in[1];
    const int*   batch= (const int*)d_in[2];
    const float* W1   = (const float*)d_in[3];
    const float* b1   = (const float*)d_in[4];
    const float* W2   = (const float*)d_in[5];
    const float* b2   = (const float*)d_in[6];
    const float* Wg1  = (const float*)d_in[7];
    const float* bg1  = (const float*)d_in[8];
    const float* Wg2  = (const float*)d_in[9];
    const float* bg2  = (const float*)d_in[10];
    const int* src = ei;
    const int* dst = ei + NE;

    char* w8 = (char*)d_ws;
    int*   cnt     = (int*)w8;                 w8 += (size_t)NN * 4;
    int*   row_ptr = (int*)w8;                 w8 += (size_t)(NN + 4) * 4;
    int*   cursor  = (int*)w8;                 w8 += (size_t)NN * 4;
    int*   bsum    = (int*)w8;                 w8 += 128 * 4;
    int2*  es      = (int2*)w8;                w8 += (size_t)NE * 8;
    float* dinv    = (float*)w8;               w8 += (size_t)NN * 4;
    float* h1      = (float*)w8;               w8 += (size_t)NN * 128 * 4;
    unsigned* gmax = (unsigned*)w8;            w8 += (size_t)NG * 256 * 4;
    float* g1      = (float*)w8;               w8 += (size_t)NG * 1024 * 4;

    // CSR build
    k_zero_int<<<(NN + 255) / 256, 256, 0, stream>>>(cnt, NN);
    k_hist<<<(NE + 255) / 256, 256, 0, stream>>>(dst, cnt, NE);
    k_prep<<<(NG * 256 + 255) / 256, 256, 0, stream>>>(cnt, dinv, (float*)gmax);
    k_bsum<<<NBLK, 256, 0, stream>>>(cnt, bsum);
    k_scan_bsum<<<1, 128, 0, stream>>>(bsum, row_ptr);
    k_scan_blocks<<<NBLK, 256, 0, stream>>>(cnt, bsum, row_ptr, cursor);
    k_fillslots<<<(NE + 255) / 256, 256, 0, stream>>>(src, dst, dinv, cursor, es, NE);

    // layer 1 (fused pair-zip gather + gemm + relu): 3125 blocks x 4 waves = 12500 tasks x 8 nodes
    k_fused1<<<NN / 32, 256, 0, stream>>>(x, row_ptr, es, dinv, W1, b1, h1);

    // layer 2 (fused pair-zip gather + gemm + relu + pool)
    k_fused2<<<NN / 32, 256, 0, stream>>>(h1, row_ptr, es, dinv, W2, b2, batch, gmax);

    // MLP head
    k_gemm3<<<NG, 256, 0, stream>>>((const float*)gmax, Wg1, bg1, g1);
    k_gemm4<<<NG, 128, 0, stream>>>(g1, Wg2, bg2, (float*)d_out);
}